// Round 4
// baseline (272.790 us; speedup 1.0000x reference)
//
#include <hip/hip_runtime.h>
#include <hip/hip_bf16.h>

#define B_  8
#define H_  512
#define L_  2048
#define D2_ 32
#define NC_ 32
#define LC_ 64    // L_/NC_
#define LCF 32    // fk kernel l-chunk

typedef __attribute__((ext_vector_type(8))) short short8;   // 8 bf16 (4 VGPRs)
typedef __attribute__((ext_vector_type(4))) float float4v;  // 4 fp32 acc

__device__ __forceinline__ float gelu_exact(float x) {
    return 0.5f * x * (1.0f + erff(x * 0.70710678118654752f));
}

__device__ __forceinline__ unsigned pack_bf16x2(float x, float y) {
    __hip_bfloat162 p = __float22bfloat162_rn(make_float2(x, y));
    return *(unsigned*)&p;
}
__device__ __forceinline__ float2 unpack_bf16x2(unsigned v) {
    __hip_bfloat162 p = *(__hip_bfloat162*)&v;
    return __bfloat1622float2(p);
}

__device__ __forceinline__ void load_lds16(const void* g, void* l) {
    __builtin_amdgcn_global_load_lds((const __attribute__((address_space(1))) unsigned int*)g,
                                     (__attribute__((address_space(3))) unsigned int*)l, 16, 0, 0);
}

// ---------------- cast W (512x512 f32) -> bf16 ----------------
__global__ void cast_w_kernel(const float* __restrict__ W, __hip_bfloat16* __restrict__ Wb) {
    int tid = blockIdx.x * 256 + threadIdx.x;
    Wb[tid] = __float2bfloat16(W[tid]);
}

// ---------------- prep: transpose params to d-major [d][h], precompute ----------------
__global__ void prep_kernel(const float* __restrict__ a, const float* __restrict__ th,
                            const float* __restrict__ bb, const float* __restrict__ cc,
                            const float* __restrict__ x0,
                            float* __restrict__ aT, float* __restrict__ thT,
                            float* __restrict__ wrT, float* __restrict__ wiT,
                            float* __restrict__ qT, float* __restrict__ gxT) {
    int tid = blockIdx.x * 256 + threadIdx.x;   // H_*D2_ = 16384; tid = d*H + h
    int h = tid & (H_ - 1);
    int d = tid >> 9;
    const float T = 1.0f / (float)(L_ - 1);
    float av = -fabsf(a[h * D2_ + d]);
    float tv = th[h * D2_ + d];
    float e  = __expf(av * T);
    aT[tid]  = av;
    thT[tid] = tv;
    wrT[tid] = e * __cosf(tv * T);
    wiT[tid] = e * __sinf(tv * T);
    qT[tid]  = bb[h * D2_ + d] * cc[h * D2_ + d];
    gxT[tid] = 2.0f * cc[h * D2_ + d] * x0[h * D2_ + d];
}

// ---------------- transpose u[b][h][l] -> uT[b][l][h] (bf16) ----------------
__global__ __launch_bounds__(256) void transpose_u_kernel(
        const float* __restrict__ u, __hip_bfloat16* __restrict__ uT) {
    __shared__ float tile[64][65];
    int l0 = blockIdx.x * 64, h0 = blockIdx.y * 64, b = blockIdx.z;
    int t = threadIdx.x;
    int tl = t & 63, tr = t >> 6;   // 4 rows per pass
    #pragma unroll
    for (int r = 0; r < 64; r += 4)
        tile[tr + r][tl] = u[((size_t)(b * H_ + h0 + tr + r)) * L_ + l0 + tl];
    __syncthreads();
    #pragma unroll
    for (int r = 0; r < 64; r += 4)
        uT[((size_t)(b * L_ + l0 + tr + r)) * H_ + h0 + tl] =
            __float2bfloat16(tile[tl][tr + r]);
}

// ---------------- fk: FKt[l*H+h] = bf16x2{ f[h,l], k0[h,l] } via p<-p*w recurrence ----
__global__ __launch_bounds__(256) void fk_v3_kernel(
        const float* __restrict__ aT, const float* __restrict__ thT,
        const float* __restrict__ qT, const float* __restrict__ gxT,
        unsigned* __restrict__ FKt) {
    int t = threadIdx.x;
    int q4 = t & 3, hl = t >> 2;          // quarter of d, h within 64
    int h  = blockIdx.y * 64 + hl;
    int l0 = blockIdx.x * LCF;
    const float T = 1.0f / (float)(L_ - 1);
    float z0 = T * (float)l0;
    float pr[8], pi[8], wr[8], wi[8], qd[8], gx[8];
    #pragma unroll
    for (int j = 0; j < 8; ++j) {
        int idx = (q4 * 8 + j) * H_ + h;
        float aa = aT[idx], tv = thT[idx];
        float e0 = __expf(aa * z0);
        pr[j] = e0 * __cosf(tv * z0);
        pi[j] = e0 * __sinf(tv * z0);
        float e1 = __expf(aa * T);
        wr[j] = e1 * __cosf(tv * T);
        wi[j] = e1 * __sinf(tv * T);
        qd[j] = qT[idx];
        gx[j] = gxT[idx];
    }
    for (int i = 0; i < LCF; ++i) {
        float fa = 0.f, ka = 0.f;
        #pragma unroll
        for (int j = 0; j < 8; ++j) {
            fa = fmaf(qd[j], pr[j], fa);
            ka = fmaf(gx[j], pr[j], ka);
            float nr = fmaf(pr[j], wr[j], -(pi[j] * wi[j]));
            float ni = fmaf(pr[j], wi[j],  (pi[j] * wr[j]));
            pr[j] = nr; pi[j] = ni;
        }
        fa += __shfl_xor(fa, 1); fa += __shfl_xor(fa, 2);
        ka += __shfl_xor(ka, 1); ka += __shfl_xor(ka, 2);
        if (q4 == 0)
            FKt[(size_t)(l0 + i) * H_ + h] = pack_bf16x2(2.0f * T * fa, ka);
    }
}

// ---------------- Pass A: chunk-local scans (broadcast u loads) ----------------
__global__ __launch_bounds__(256) void scan_chunk_kernel(
        const float* __restrict__ u, const float* __restrict__ a,
        const float* __restrict__ th, unsigned* __restrict__ E) {
    int tid = blockIdx.x * 256 + threadIdx.x;   // B_*H_*D2_*NC_ threads
    int d  = tid & (D2_ - 1);
    int c  = (tid >> 5) & (NC_ - 1);
    int bh = tid / (D2_ * NC_);
    int h  = bh & (H_ - 1);
    const float T = 1.0f / (float)(L_ - 1);
    float aa  = -fabsf(a[h * D2_ + d]);
    float ea  = __expf(aa * T);
    float tT  = th[h * D2_ + d] * T;
    float wr  = ea * __cosf(tT);
    float wi  = ea * __sinf(tT);
    const float* ur = u + (size_t)bh * L_ + c * LC_;
    float sr = 0.f, si = 0.f;
    #pragma unroll 8
    for (int i = 0; i < LC_; ++i) {
        float ul = ur[i];
        float nr = fmaf(sr, wr, fmaf(-si, wi, ul));
        float ni = fmaf(sr, wi, si * wr);
        sr = nr; si = ni;
    }
    E[((size_t)bh * NC_ + c) * D2_ + d] = pack_bf16x2(sr, si);
}

// ---------------- combine: in-place E[c] -> carry ENTERING chunk c ----------------
__global__ __launch_bounds__(256) void combine_kernel(
        const float* __restrict__ a, const float* __restrict__ th,
        unsigned* __restrict__ E) {
    int tid = blockIdx.x * 256 + threadIdx.x;   // B_*H_*D2_ = 131072
    int d  = tid & (D2_ - 1);
    int bh = tid >> 5;
    int h  = bh & (H_ - 1);
    const float T = 1.0f / (float)(L_ - 1);
    float aa  = -fabsf(a[h * D2_ + d]);
    float eC  = __expf(aa * T * (float)LC_);
    float tC  = th[h * D2_ + d] * T * (float)LC_;
    float Wr  = eC * __cosf(tC);
    float Wi  = eC * __sinf(tC);
    float sr = 0.f, si = 0.f;
    for (int c = 0; c < NC_; ++c) {
        size_t idx = ((size_t)bh * NC_ + c) * D2_ + d;
        float2 e = unpack_bf16x2(E[idx]);
        E[idx] = pack_bf16x2(sr, si);            // carry entering chunk c
        float nr = fmaf(sr, Wr, fmaf(-si, Wi, e.x));
        float ni = fmaf(sr, Wi, fmaf(si, Wr, e.y));
        sr = nr; si = ni;
    }
}

// ---------------- Pass B: d-split x4, fully coalesced ----------------
__global__ __launch_bounds__(256) void scan_full_v3(
        const __hip_bfloat16* __restrict__ uT, const float* __restrict__ wrT,
        const float* __restrict__ wiT, const float* __restrict__ qT,
        const float* __restrict__ Dp, const unsigned* __restrict__ E,
        const unsigned* __restrict__ FKt, __hip_bfloat16* __restrict__ yT) {
    int t = threadIdx.x;
    int q4 = t & 3;          // which 8 of the 32 d's
    int hl = t >> 2;         // 0..63
    int c = blockIdx.x, b = blockIdx.z;
    int h = blockIdx.y * 64 + hl;
    int bh = b * H_ + h;
    const float T = 1.0f / (float)(L_ - 1);

    float wr[8], wi[8], qd[8], sr[8], si[8];
    float qsum = 0.f;
    #pragma unroll
    for (int j = 0; j < 8; ++j) {
        int d = q4 * 8 + j;
        int idx = d * H_ + h;
        wr[j] = wrT[idx];
        wi[j] = wiT[idx];
        qd[j] = qT[idx];
        qsum += qd[j];
        float2 s = unpack_bf16x2(E[((size_t)bh * NC_ + c) * D2_ + d]);
        sr[j] = s.x; si[j] = s.y;
    }
    qsum += __shfl_xor(qsum, 1);
    qsum += __shfl_xor(qsum, 2);
    float f0 = 2.0f * T * qsum;
    float u0 = __bfloat162float(uT[(size_t)(b * L_) * H_ + h]);
    float Dh = Dp[h];

    const __hip_bfloat16* up = uT + ((size_t)b * L_ + c * LC_) * H_ + h;
    const unsigned* fp = FKt + (size_t)(c * LC_) * H_ + h;
    __hip_bfloat16* yp = yT + ((size_t)b * L_ + c * LC_) * H_ + h;

    for (int i = 0; i < LC_; ++i) {
        float ul = __bfloat162float(up[(size_t)i * H_]);
        float2 fk = unpack_bf16x2(fp[(size_t)i * H_]);
        float dta = 0.f, dtb = 0.f;
        #pragma unroll
        for (int j = 0; j < 8; ++j) {
            float nr = fmaf(sr[j], wr[j], fmaf(-si[j], wi[j], ul));
            float ni = fmaf(sr[j], wi[j], si[j] * wr[j]);
            sr[j] = nr; si[j] = ni;
            if (j & 1) dtb = fmaf(qd[j], nr, dtb);
            else       dta = fmaf(qd[j], nr, dta);
        }
        float dot = dta + dtb;
        dot += __shfl_xor(dot, 1);
        dot += __shfl_xor(dot, 2);
        float y = fmaf(2.0f * T, dot, fk.y)        // conv + k0
                  - 0.5f * (f0 * ul + fk.x * u0)   // trapezoid correction
                  + Dh * ul;                       // skip D*u
        if (q4 == 0)
            yp[(size_t)i * H_] = __float2bfloat16(gelu_exact(y));
    }
}

// ---------------- gemm: out[b,h,l] = sum_f W[h,f] * yT[b,l,f] + bias[h] ----------------
__global__ __launch_bounds__(256) void gemm_kernel(
        const __hip_bfloat16* __restrict__ Wb, const __hip_bfloat16* __restrict__ yT,
        const float* __restrict__ bias, float* __restrict__ out) {
    __shared__ __align__(16) short As[128 * 32];
    __shared__ __align__(16) short Bs[128 * 32];
    int l0 = blockIdx.x * 128;
    int h0 = blockIdx.y * 128;
    int b  = blockIdx.z;
    int t    = threadIdx.x;
    int lane = t & 63, wave = t >> 6;
    int m_off = (wave >> 1) * 64, n_off = (wave & 1) * 64;
    int quad = lane >> 4, ln = lane & 15;

    float4v acc[4][4];
    #pragma unroll
    for (int mt = 0; mt < 4; ++mt)
        #pragma unroll
        for (int nt = 0; nt < 4; ++nt)
            acc[mt][nt] = (float4v){0.f, 0.f, 0.f, 0.f};

    const short* Wg = (const short*)Wb;
    const short* Yg = (const short*)(yT + (size_t)b * L_ * H_);

    int r  = t >> 2;
    int qd = t & 3;

    for (int kt = 0; kt < 16; ++kt) {
        int k0 = kt * 32;
        load_lds16(Wg + (h0 + r)      * 512 + k0 + qd * 8, &As[t * 8]);
        load_lds16(Wg + (h0 + r + 64) * 512 + k0 + qd * 8, &As[(t + 256) * 8]);
        load_lds16(Yg + (size_t)(l0 + r)      * 512 + k0 + qd * 8, &Bs[t * 8]);
        load_lds16(Yg + (size_t)(l0 + r + 64) * 512 + k0 + qd * 8, &Bs[(t + 256) * 8]);
        __syncthreads();

        short8 af[4], bf[4];
        #pragma unroll
        for (int mt = 0; mt < 4; ++mt)
            af[mt] = *(const short8*)&As[(m_off + mt * 16 + ln) * 32 + quad * 8];
        #pragma unroll
        for (int nt = 0; nt < 4; ++nt)
            bf[nt] = *(const short8*)&Bs[(n_off + nt * 16 + ln) * 32 + quad * 8];
        #pragma unroll
        for (int mt = 0; mt < 4; ++mt)
            #pragma unroll
            for (int nt = 0; nt < 4; ++nt)
                acc[mt][nt] = __builtin_amdgcn_mfma_f32_16x16x32_bf16(
                    af[mt], bf[nt], acc[mt][nt], 0, 0, 0);
        __syncthreads();
    }

    #pragma unroll
    for (int mt = 0; mt < 4; ++mt) {
        #pragma unroll
        for (int nt = 0; nt < 4; ++nt) {
            int hh = h0 + m_off + mt * 16 + quad * 4;
            int ll = l0 + n_off + nt * 16 + ln;
            #pragma unroll
            for (int r2 = 0; r2 < 4; ++r2)
                out[((size_t)(b * H_ + hh + r2)) * L_ + ll] = acc[mt][nt][r2] + bias[hh + r2];
        }
    }
}

extern "C" void kernel_launch(void* const* d_in, const int* in_sizes, int n_in,
                              void* d_out, int out_size, void* d_ws, size_t ws_size,
                              hipStream_t stream) {
    const float* u    = (const float*)d_in[0];
    const float* a    = (const float*)d_in[1];
    const float* th   = (const float*)d_in[2];
    const float* bb   = (const float*)d_in[3];
    const float* cc   = (const float*)d_in[4];
    const float* x0   = (const float*)d_in[5];
    const float* Dp   = (const float*)d_in[6];
    const float* W    = (const float*)d_in[7];
    const float* bias = (const float*)d_in[8];
    float* out = (float*)d_out;
    char* ws = (char*)d_ws;

    // layout (53.4 MiB): uT 16M | FKt 4M @16M | E 16M @20M | yT 16M @36M | Wb 0.5M @52M
    // | params 6x64K @52.5M
    __hip_bfloat16* uT  = (__hip_bfloat16*)ws;
    unsigned*       FKt = (unsigned*)(ws + (16ull << 20));
    unsigned*       E   = (unsigned*)(ws + (20ull << 20));
    __hip_bfloat16* yT  = (__hip_bfloat16*)(ws + (36ull << 20));
    __hip_bfloat16* Wb  = (__hip_bfloat16*)(ws + (52ull << 20));
    float* pbase = (float*)(ws + (52ull << 20) + (512ull << 10));
    float *aT = pbase, *thT = pbase + 16384, *wrT = pbase + 2*16384,
          *wiT = pbase + 3*16384, *qT = pbase + 4*16384, *gxT = pbase + 5*16384;

    hipLaunchKernelGGL(cast_w_kernel,     dim3(1024),      dim3(256), 0, stream, W, Wb);
    hipLaunchKernelGGL(prep_kernel,       dim3(64),        dim3(256), 0, stream,
                       a, th, bb, cc, x0, aT, thT, wrT, wiT, qT, gxT);
    hipLaunchKernelGGL(transpose_u_kernel,dim3(32, 8, 8),  dim3(256), 0, stream, u, uT);
    hipLaunchKernelGGL(fk_v3_kernel,      dim3(L_/LCF, 8), dim3(256), 0, stream,
                       aT, thT, qT, gxT, FKt);
    hipLaunchKernelGGL(scan_chunk_kernel, dim3(B_*H_*D2_*NC_/256), dim3(256), 0, stream,
                       u, a, th, E);
    hipLaunchKernelGGL(combine_kernel,    dim3(512),       dim3(256), 0, stream, a, th, E);
    hipLaunchKernelGGL(scan_full_v3,      dim3(NC_, 8, 8), dim3(256), 0, stream,
                       uT, wrT, wiT, qT, Dp, E, FKt, yT);
    hipLaunchKernelGGL(gemm_kernel,       dim3(16, 4, 8),  dim3(256), 0, stream,
                       Wb, yT, bias, out);
}

// Round 5
// 217.610 us; speedup vs baseline: 1.2536x; 1.2536x over previous
//
#include <hip/hip_runtime.h>
#include <hip/hip_bf16.h>

#define B_  8
#define H_  512
#define L_  2048
#define D2_ 32
#define NC_ 32
#define LC_ 64    // L_/NC_
#define LCF 32    // fk kernel l-chunk

typedef __attribute__((ext_vector_type(8))) short short8;   // 8 bf16 (4 VGPRs)
typedef __attribute__((ext_vector_type(4))) float float4v;  // 4 fp32 acc

__device__ __forceinline__ float gelu_exact(float x) {
    return 0.5f * x * (1.0f + erff(x * 0.70710678118654752f));
}

__device__ __forceinline__ unsigned pack_bf16x2(float x, float y) {
    __hip_bfloat162 p = __float22bfloat162_rn(make_float2(x, y));
    return *(unsigned*)&p;
}
__device__ __forceinline__ float2 unpack_bf16x2(unsigned v) {
    __hip_bfloat162 p = *(__hip_bfloat162*)&v;
    return __bfloat1622float2(p);
}

__device__ __forceinline__ void load_lds16(const void* g, void* l) {
    __builtin_amdgcn_global_load_lds((const __attribute__((address_space(1))) unsigned int*)g,
                                     (__attribute__((address_space(3))) unsigned int*)l, 16, 0, 0);
}

// ---------------- cast W -> bf16, fused param prep ----------------
__global__ void cast_prep_kernel(const float* __restrict__ W, __hip_bfloat16* __restrict__ Wb,
                                 const float* __restrict__ a, const float* __restrict__ th,
                                 const float* __restrict__ bb, const float* __restrict__ cc,
                                 const float* __restrict__ x0,
                                 float* __restrict__ aT, float* __restrict__ thT,
                                 float* __restrict__ qT, float* __restrict__ gxT,
                                 float* __restrict__ WRh, float* __restrict__ WIh,
                                 float* __restrict__ Qh) {
    int tid = blockIdx.x * 256 + threadIdx.x;   // 262144
    Wb[tid] = __float2bfloat16(W[tid]);
    if (tid < H_ * D2_) {                        // tid = d*H + h (d-major)
        int h = tid & (H_ - 1);
        int d = tid >> 9;
        const float T = 1.0f / (float)(L_ - 1);
        float av = -fabsf(a[h * D2_ + d]);
        float tv = th[h * D2_ + d];
        float q  = bb[h * D2_ + d] * cc[h * D2_ + d];
        float e  = __expf(av * T);
        float wr = e * __cosf(tv * T);
        float wi = e * __sinf(tv * T);
        aT[tid]  = av;
        thT[tid] = tv;
        qT[tid]  = q;
        gxT[tid] = 2.0f * cc[h * D2_ + d] * x0[h * D2_ + d];
        WRh[h * D2_ + d] = wr;      // h-major copies for the scan kernels
        WIh[h * D2_ + d] = wi;
        Qh [h * D2_ + d] = q;
    }
}

// ---------------- fk: FKf[h*L + l] = bf16x2{ f[h,l], k0[h,l] } ----------------
__global__ __launch_bounds__(256) void fk_kernel(
        const float* __restrict__ aT, const float* __restrict__ thT,
        const float* __restrict__ qT, const float* __restrict__ gxT,
        unsigned* __restrict__ FKf) {
    int t = threadIdx.x;
    int q4 = t & 3, hl = t >> 2;          // quarter of d, h within 64
    int h  = blockIdx.y * 64 + hl;
    int l0 = blockIdx.x * LCF;
    const float T = 1.0f / (float)(L_ - 1);
    float z0 = T * (float)l0;
    float pr[8], pi[8], wr[8], wi[8], qd[8], gx[8];
    #pragma unroll
    for (int j = 0; j < 8; ++j) {
        int idx = (q4 * 8 + j) * H_ + h;
        float aa = aT[idx], tv = thT[idx];
        float e0 = __expf(aa * z0);
        pr[j] = e0 * __cosf(tv * z0);
        pi[j] = e0 * __sinf(tv * z0);
        float e1 = __expf(aa * T);
        wr[j] = e1 * __cosf(tv * T);
        wi[j] = e1 * __sinf(tv * T);
        qd[j] = qT[idx];
        gx[j] = gxT[idx];
    }
    for (int i = 0; i < LCF; ++i) {
        float fa = 0.f, ka = 0.f;
        #pragma unroll
        for (int j = 0; j < 8; ++j) {
            fa = fmaf(qd[j], pr[j], fa);
            ka = fmaf(gx[j], pr[j], ka);
            float nr = fmaf(pr[j], wr[j], -(pi[j] * wi[j]));
            float ni = fmaf(pr[j], wi[j],  (pi[j] * wr[j]));
            pr[j] = nr; pi[j] = ni;
        }
        fa += __shfl_xor(fa, 1); fa += __shfl_xor(fa, 2);
        ka += __shfl_xor(ka, 1); ka += __shfl_xor(ka, 2);
        if (q4 == 0)
            FKf[(size_t)h * L_ + l0 + i] = pack_bf16x2(2.0f * T * fa, ka);
    }
}

// ---------------- Pass A: wave-per-h chunk-local scans -> E ----------------
// block 128 = 2 waves, same h; lane -> (b,c) pair. All 32 states per lane.
__global__ __launch_bounds__(128) void scan_a_kernel(
        const float* __restrict__ u, const float* __restrict__ WRh,
        const float* __restrict__ WIh, unsigned* __restrict__ E) {
    int h = blockIdx.x;
    int p = blockIdx.y * 128 + threadIdx.x;   // 0..255 = (b,c)
    int b = p >> 5;
    int c = p & (NC_ - 1);
    float wr[D2_], wi[D2_];
    #pragma unroll
    for (int j = 0; j < D2_; ++j) {
        wr[j] = WRh[h * D2_ + j];   // wave-uniform -> scalar loads
        wi[j] = WIh[h * D2_ + j];
    }
    float sr[D2_], si[D2_];
    #pragma unroll
    for (int j = 0; j < D2_; ++j) { sr[j] = 0.f; si[j] = 0.f; }

    const float4* up = (const float4*)(u + (size_t)(b * H_ + h) * L_ + c * LC_);
    for (int i4 = 0; i4 < LC_ / 4; ++i4) {
        float4 u4 = up[i4];
        float us[4] = {u4.x, u4.y, u4.z, u4.w};
        #pragma unroll
        for (int s = 0; s < 4; ++s) {
            float ul = us[s];
            #pragma unroll
            for (int j = 0; j < D2_; ++j) {
                float nr = fmaf(sr[j], wr[j], fmaf(-si[j], wi[j], ul));
                float ni = fmaf(sr[j], wi[j], si[j] * wr[j]);
                sr[j] = nr; si[j] = ni;
            }
        }
    }
    unsigned* ep = E + ((size_t)(b * H_ + h) * NC_ + c) * D2_;
    #pragma unroll
    for (int j = 0; j < D2_; ++j) ep[j] = pack_bf16x2(sr[j], si[j]);
}

// ---------------- combine: in-place E[c] -> carry ENTERING chunk c ----------------
__global__ __launch_bounds__(256) void combine_kernel(
        const float* __restrict__ a, const float* __restrict__ th,
        unsigned* __restrict__ E) {
    int tid = blockIdx.x * 256 + threadIdx.x;   // B_*H_*D2_ = 131072
    int d  = tid & (D2_ - 1);
    int bh = tid >> 5;
    int h  = bh & (H_ - 1);
    const float T = 1.0f / (float)(L_ - 1);
    float aa  = -fabsf(a[h * D2_ + d]);
    float eC  = __expf(aa * T * (float)LC_);
    float tC  = th[h * D2_ + d] * T * (float)LC_;
    float Wr  = eC * __cosf(tC);
    float Wi  = eC * __sinf(tC);
    float sr = 0.f, si = 0.f;
    for (int c = 0; c < NC_; ++c) {
        size_t idx = ((size_t)bh * NC_ + c) * D2_ + d;
        float2 e = unpack_bf16x2(E[idx]);
        E[idx] = pack_bf16x2(sr, si);            // carry entering chunk c
        float nr = fmaf(sr, Wr, fmaf(-si, Wi, e.x));
        float ni = fmaf(sr, Wi, fmaf(si, Wr, e.y));
        sr = nr; si = ni;
    }
}

// ---------------- Pass B: wave-per-h full scan, fused epilogue, y[b][h][l] ----------------
__global__ __launch_bounds__(128) void scan_b_kernel(
        const float* __restrict__ u, const float* __restrict__ WRh,
        const float* __restrict__ WIh, const float* __restrict__ Qh,
        const float* __restrict__ Dp, const unsigned* __restrict__ E,
        const unsigned* __restrict__ FKf, __hip_bfloat16* __restrict__ y) {
    int h = blockIdx.x;
    int p = blockIdx.y * 128 + threadIdx.x;   // (b,c)
    int b = p >> 5;
    int c = p & (NC_ - 1);
    const float T = 1.0f / (float)(L_ - 1);

    float wr[D2_], wi[D2_], q[D2_];
    float qsum = 0.f;
    #pragma unroll
    for (int j = 0; j < D2_; ++j) {
        wr[j] = WRh[h * D2_ + j];   // wave-uniform
        wi[j] = WIh[h * D2_ + j];
        q[j]  = Qh[h * D2_ + j];
        qsum += q[j];
    }
    float f0 = 2.0f * T * qsum;
    float Dh = Dp[h];

    float sr[D2_], si[D2_];
    const uint4* ep = (const uint4*)(E + ((size_t)(b * H_ + h) * NC_ + c) * D2_);
    #pragma unroll
    for (int j8 = 0; j8 < D2_ / 4; ++j8) {
        uint4 ev = ep[j8];
        unsigned evs[4] = {ev.x, ev.y, ev.z, ev.w};
        #pragma unroll
        for (int k = 0; k < 4; ++k) {
            float2 s = unpack_bf16x2(evs[k]);
            sr[j8 * 4 + k] = s.x; si[j8 * 4 + k] = s.y;
        }
    }
    float u0 = u[(size_t)(b * H_ + h) * L_];

    const float4* up = (const float4*)(u + (size_t)(b * H_ + h) * L_ + c * LC_);
    const uint4*  fp = (const uint4*)(FKf + (size_t)h * L_ + c * LC_);
    __hip_bfloat16* yp = y + (size_t)(b * H_ + h) * L_ + c * LC_;

    unsigned ybuf[4];
    for (int i4 = 0; i4 < LC_ / 4; ++i4) {
        float4 u4 = up[i4];
        uint4  f4 = fp[i4];
        float us[4] = {u4.x, u4.y, u4.z, u4.w};
        unsigned fs[4] = {f4.x, f4.y, f4.z, f4.w};
        #pragma unroll
        for (int s = 0; s < 4; ++s) {
            float ul = us[s];
            float2 fk = unpack_bf16x2(fs[s]);
            float d0 = 0.f, d1 = 0.f, d2 = 0.f, d3 = 0.f;
            #pragma unroll
            for (int j = 0; j < D2_; ++j) {
                float nr = fmaf(sr[j], wr[j], fmaf(-si[j], wi[j], ul));
                float ni = fmaf(sr[j], wi[j], si[j] * wr[j]);
                sr[j] = nr; si[j] = ni;
                if ((j & 3) == 0)      d0 = fmaf(q[j], nr, d0);
                else if ((j & 3) == 1) d1 = fmaf(q[j], nr, d1);
                else if ((j & 3) == 2) d2 = fmaf(q[j], nr, d2);
                else                   d3 = fmaf(q[j], nr, d3);
            }
            float dot = (d0 + d1) + (d2 + d3);
            float yv = fmaf(2.0f * T, dot, fk.y)        // conv + k0
                       - 0.5f * (f0 * ul + fk.x * u0)   // trapezoid correction
                       + Dh * ul;                       // skip D*u
            float g = gelu_exact(yv);
            int slot = (i4 & 1) * 2 + (s >> 1);
            if ((s & 1) == 0) ybuf[slot] = pack_bf16x2(g, 0.f);
            else {
                __hip_bfloat16 gb = __float2bfloat16(g);
                ybuf[slot] = (ybuf[slot] & 0xFFFFu) | ((unsigned)(*(unsigned short*)&gb) << 16);
            }
        }
        if (i4 & 1)
            *(uint4*)(yp + (i4 - 1) * 4) = *(uint4*)ybuf;
    }
}

// ---------------- transpose y[b][f][l] -> yT[b][l][f] (bf16) ----------------
__global__ __launch_bounds__(256) void transpose_y_kernel(
        const __hip_bfloat16* __restrict__ y, __hip_bfloat16* __restrict__ yT) {
    __shared__ short tile[64][72];
    int l0 = blockIdx.x * 64, f0 = blockIdx.y * 64, b = blockIdx.z;
    int t = threadIdx.x;
    int row = t >> 3, col8 = (t & 7) * 8;
    const short* yg = (const short*)y + (size_t)b * H_ * L_;
    #pragma unroll
    for (int r2 = 0; r2 < 64; r2 += 32)
        *(uint4*)&tile[row + r2][col8] =
            *(const uint4*)&yg[(size_t)(f0 + row + r2) * L_ + l0 + col8];
    __syncthreads();
    short* og = (short*)yT + (size_t)b * L_ * H_;
    #pragma unroll
    for (int r2 = 0; r2 < 64; r2 += 32) {
        int lrow = row + r2;
        short v[8];
        #pragma unroll
        for (int j = 0; j < 8; ++j) v[j] = tile[col8 + j][lrow];
        *(uint4*)&og[(size_t)(l0 + lrow) * H_ + f0 + col8] = *(uint4*)v;
    }
}

// ---------------- gemm: out[b,h,l] = sum_f W[h,f] * yT[b,l,f] + bias[h] ----------------
__global__ __launch_bounds__(256) void gemm_kernel(
        const __hip_bfloat16* __restrict__ Wb, const __hip_bfloat16* __restrict__ yT,
        const float* __restrict__ bias, float* __restrict__ out) {
    __shared__ __align__(16) short As[128 * 32];
    __shared__ __align__(16) short Bs[128 * 32];
    int l0 = blockIdx.x * 128;
    int h0 = blockIdx.y * 128;
    int b  = blockIdx.z;
    int t    = threadIdx.x;
    int lane = t & 63, wave = t >> 6;
    int m_off = (wave >> 1) * 64, n_off = (wave & 1) * 64;
    int quad = lane >> 4, ln = lane & 15;

    float4v acc[4][4];
    #pragma unroll
    for (int mt = 0; mt < 4; ++mt)
        #pragma unroll
        for (int nt = 0; nt < 4; ++nt)
            acc[mt][nt] = (float4v){0.f, 0.f, 0.f, 0.f};

    const short* Wg = (const short*)Wb;
    const short* Yg = (const short*)(yT + (size_t)b * L_ * H_);

    int r  = t >> 2;
    int qd = t & 3;

    for (int kt = 0; kt < 16; ++kt) {
        int k0 = kt * 32;
        load_lds16(Wg + (h0 + r)      * 512 + k0 + qd * 8, &As[t * 8]);
        load_lds16(Wg + (h0 + r + 64) * 512 + k0 + qd * 8, &As[(t + 256) * 8]);
        load_lds16(Yg + (size_t)(l0 + r)      * 512 + k0 + qd * 8, &Bs[t * 8]);
        load_lds16(Yg + (size_t)(l0 + r + 64) * 512 + k0 + qd * 8, &Bs[(t + 256) * 8]);
        __syncthreads();

        short8 af[4], bf[4];
        #pragma unroll
        for (int mt = 0; mt < 4; ++mt)
            af[mt] = *(const short8*)&As[(m_off + mt * 16 + ln) * 32 + quad * 8];
        #pragma unroll
        for (int nt = 0; nt < 4; ++nt)
            bf[nt] = *(const short8*)&Bs[(n_off + nt * 16 + ln) * 32 + quad * 8];
        #pragma unroll
        for (int mt = 0; mt < 4; ++mt)
            #pragma unroll
            for (int nt = 0; nt < 4; ++nt)
                acc[mt][nt] = __builtin_amdgcn_mfma_f32_16x16x32_bf16(
                    af[mt], bf[nt], acc[mt][nt], 0, 0, 0);
        __syncthreads();
    }

    #pragma unroll
    for (int mt = 0; mt < 4; ++mt) {
        #pragma unroll
        for (int nt = 0; nt < 4; ++nt) {
            int hh = h0 + m_off + mt * 16 + quad * 4;
            int ll = l0 + n_off + nt * 16 + ln;
            #pragma unroll
            for (int r2 = 0; r2 < 4; ++r2)
                out[((size_t)(b * H_ + hh + r2)) * L_ + ll] = acc[mt][nt][r2] + bias[hh + r2];
        }
    }
}

extern "C" void kernel_launch(void* const* d_in, const int* in_sizes, int n_in,
                              void* d_out, int out_size, void* d_ws, size_t ws_size,
                              hipStream_t stream) {
    const float* u    = (const float*)d_in[0];
    const float* a    = (const float*)d_in[1];
    const float* th   = (const float*)d_in[2];
    const float* bb   = (const float*)d_in[3];
    const float* cc   = (const float*)d_in[4];
    const float* x0   = (const float*)d_in[5];
    const float* Dp   = (const float*)d_in[6];
    const float* W    = (const float*)d_in[7];
    const float* bias = (const float*)d_in[8];
    float* out = (float*)d_out;
    char* ws = (char*)d_ws;

    // layout (~53 MB): FKf 4M @0 | E 16M @4M | y 16M @20M | yT 16M @36M | Wb 0.5M @52M
    // | params 7x64K @52.5M
    unsigned*       FKf = (unsigned*)ws;
    unsigned*       E   = (unsigned*)(ws + (4ull  << 20));
    __hip_bfloat16* y   = (__hip_bfloat16*)(ws + (20ull << 20));
    __hip_bfloat16* yT  = (__hip_bfloat16*)(ws + (36ull << 20));
    __hip_bfloat16* Wb  = (__hip_bfloat16*)(ws + (52ull << 20));
    float* pbase = (float*)(ws + (52ull << 20) + (512ull << 10));
    float *aT = pbase,            *thT = pbase + 16384,   *qT  = pbase + 2*16384,
          *gxT = pbase + 3*16384, *WRh = pbase + 4*16384, *WIh = pbase + 5*16384,
          *Qh  = pbase + 6*16384;

    hipLaunchKernelGGL(cast_prep_kernel,  dim3(1024),      dim3(256), 0, stream,
                       W, Wb, a, th, bb, cc, x0, aT, thT, qT, gxT, WRh, WIh, Qh);
    hipLaunchKernelGGL(fk_kernel,         dim3(L_/LCF, 8), dim3(256), 0, stream,
                       aT, thT, qT, gxT, FKf);
    hipLaunchKernelGGL(scan_a_kernel,     dim3(H_, 2),     dim3(128), 0, stream,
                       u, WRh, WIh, E);
    hipLaunchKernelGGL(combine_kernel,    dim3(512),       dim3(256), 0, stream, a, th, E);
    hipLaunchKernelGGL(scan_b_kernel,     dim3(H_, 2),     dim3(128), 0, stream,
                       u, WRh, WIh, Qh, Dp, E, FKf, y);
    hipLaunchKernelGGL(transpose_y_kernel,dim3(32, 8, 8),  dim3(256), 0, stream, y, yT);
    hipLaunchKernelGGL(gemm_kernel,       dim3(16, 4, 8),  dim3(256), 0, stream,
                       Wb, yT, bias, out);
}